// Round 1
// baseline (762.228 us; speedup 1.0000x reference)
//
#include <hip/hip_runtime.h>
#include <stdint.h>

#define HIDDEN  2560
#define NHEADS  32
#define HEAD    80
#define DSTRIDE 128          // Q/K padded head stride (multiple of 32 for MFMA K)
#define SEQ     2048
#define BATCH   2
#define M_TOTAL (BATCH*SEQ)  // 4096
#define QKV_N   (3*HIDDEN)   // 7680

typedef __attribute__((ext_vector_type(8))) short  short8;
typedef __attribute__((ext_vector_type(4))) float  floatx4;
typedef __attribute__((ext_vector_type(4))) float  fvec4;
typedef __attribute__((ext_vector_type(4))) unsigned short usvec4;

__device__ __forceinline__ unsigned short f2bf(float x){
  union { float f; unsigned u; } v; v.f = x;
  unsigned r = v.u + 0x7fffu + ((v.u >> 16) & 1u);
  return (unsigned short)(r >> 16);
}
__device__ __forceinline__ float bf2f(unsigned short h){
  union { unsigned u; float f; } v; v.u = ((unsigned)h) << 16;
  return v.f;
}

__device__ __forceinline__ void gload16(const void* g, void* l){
  __builtin_amdgcn_global_load_lds(
    (const __attribute__((address_space(1))) void*)g,
    (__attribute__((address_space(3))) void*)l, 16, 0, 0);
}

// ---------------- f32 -> bf16 convert ----------------
__global__ __launch_bounds__(256)
void convert_f32_bf16(const float* __restrict__ src, unsigned short* __restrict__ dst, int n4){
  int idx = blockIdx.x*blockDim.x + threadIdx.x;
  int stride = gridDim.x*blockDim.x;
  for (int i = idx; i < n4; i += stride){
    fvec4 v = *(const fvec4*)(src + (size_t)i*4);
    usvec4 o;
    o[0]=f2bf(v[0]); o[1]=f2bf(v[1]); o[2]=f2bf(v[2]); o[3]=f2bf(v[3]);
    *(usvec4*)(dst + (size_t)i*4) = o;
  }
}

// ---------------- GEMM: C[M,N] = A[M,K] * B[N,K]^T + bias ----------------
// 128x128 tile, BK=64, 4 waves (each 64x64), global_load_lds staging,
// XOR-swizzled LDS (swizzle on pre-permuted global source + swizzled ds_read).
template<bool OUT_BF16>
__global__ __launch_bounds__(256)
void gemm_bt(const unsigned short* __restrict__ A, const unsigned short* __restrict__ Bm,
             const float* __restrict__ bias, void* __restrict__ Cout,
             int M, int N, int K)
{
  __shared__ __align__(16) unsigned short Alds[128*64];
  __shared__ __align__(16) unsigned short Blds[128*64];
  const int tid  = threadIdx.x;
  const int lane = tid & 63;
  const int wid  = tid >> 6;
  const int wr   = wid >> 1, wc = wid & 1;
  const int rowA0 = blockIdx.y * 128;
  const int rowB0 = blockIdx.x * 128;
  const int l15 = lane & 15, lg = lane >> 4;

  floatx4 acc[4][4];
  #pragma unroll
  for (int i=0;i<4;i++)
    #pragma unroll
    for (int j=0;j<4;j++) acc[i][j] = (floatx4)0.0f;

  // staging geometry: chunk c = wid*4+i covers LDS elems [c*512, c*512+512)
  int srow[4], scol[4];
  #pragma unroll
  for (int i=0;i<4;i++){
    int c = wid*4 + i;
    int e = c*512 + lane*8;
    int row = e >> 6;            // 64 elems per row
    int col8 = (e >> 3) & 7;     // 16B chunk within row
    srow[i] = row;
    scol[i] = ((col8 ^ (row & 7)) << 3);  // pre-swizzled source column
  }

  for (int k0 = 0; k0 < K; k0 += 64){
    #pragma unroll
    for (int i=0;i<4;i++){
      int c = wid*4 + i;
      gload16(A  + (size_t)(rowA0 + srow[i])*K + k0 + scol[i], &Alds[c*512]);
      gload16(Bm + (size_t)(rowB0 + srow[i])*K + k0 + scol[i], &Blds[c*512]);
    }
    __syncthreads();
    #pragma unroll
    for (int kk = 0; kk < 64; kk += 32){
      short8 af[4], bfv[4];
      #pragma unroll
      for (int mi=0; mi<4; mi++){
        int r = wr*64 + mi*16 + l15;
        int ch = ((kk>>3) + lg) ^ (r & 7);
        af[mi] = *(const short8*)&Alds[r*64 + ch*8];
      }
      #pragma unroll
      for (int ni=0; ni<4; ni++){
        int r = wc*64 + ni*16 + l15;
        int ch = ((kk>>3) + lg) ^ (r & 7);
        bfv[ni] = *(const short8*)&Blds[r*64 + ch*8];
      }
      #pragma unroll
      for (int mi=0; mi<4; mi++)
        #pragma unroll
        for (int ni=0; ni<4; ni++)
          acc[mi][ni] = __builtin_amdgcn_mfma_f32_16x16x32_bf16(af[mi], bfv[ni], acc[mi][ni], 0, 0, 0);
    }
    __syncthreads();
  }

  #pragma unroll
  for (int mi=0; mi<4; mi++){
    #pragma unroll
    for (int ni=0; ni<4; ni++){
      int col = rowB0 + wc*64 + ni*16 + l15;
      float bs = bias[col];
      #pragma unroll
      for (int r=0;r<4;r++){
        int row = rowA0 + wr*64 + mi*16 + lg*4 + r;
        float v = acc[mi][ni][r] + bs;
        if (OUT_BF16) ((unsigned short*)Cout)[(size_t)row*N + col] = f2bf(v);
        else          ((float*)Cout)[(size_t)row*N + col] = v;
      }
    }
  }
}

// ---------------- RoPE + scatter to attention layouts ----------------
// qkv [B,S,7680] bf16 -> Qp,Kp [B,H,S,128] (rope on d<32, zeros d>=80),
//                        Vt [B,H,80,S] (transposed)
__global__ __launch_bounds__(256)
void rope_scatter(const unsigned short* __restrict__ qkv,
                  const int* __restrict__ pos_ids,
                  unsigned short* __restrict__ Qp, unsigned short* __restrict__ Kp,
                  unsigned short* __restrict__ Vt)
{
  __shared__ float cosb[128*16];
  __shared__ float sinb[128*16];
  __shared__ __align__(16) unsigned short vtile[128*88];
  const int tid = threadIdx.x;
  const int blk = blockIdx.x;
  const int st = blk & 15, h = (blk >> 4) & 31, b = blk >> 9;
  const int s0 = st*128;

  // phase 0: cos/sin table  (inv_freq[i] = 10000^(-i/16))
  for (int idx = tid; idx < 128*16; idx += 256){
    int sl = idx >> 4, i = idx & 15;
    float p = (float)pos_ids[b*SEQ + s0 + sl];
    float inv = exp2f(-(float)i * (13.287712379549449f/16.0f));
    float ang = p * inv;
    cosb[idx] = cosf(ang);
    sinb[idx] = sinf(ang);
  }
  __syncthreads();

  const size_t qkrow = (size_t)(b*SEQ + s0)*QKV_N;
  const size_t obase = ((size_t)(b*NHEADS + h)*SEQ + s0)*DSTRIDE;
  #pragma unroll
  for (int part = 0; part < 2; part++){
    const int cbase = part*HIDDEN + h*HEAD;
    unsigned short* outp = part ? Kp : Qp;
    for (int idx = tid; idx < 128*DSTRIDE; idx += 256){
      int sl = idx >> 7, d = idx & 127;
      const size_t rb = qkrow + (size_t)sl*QKV_N + cbase;
      float v;
      if (d < 16){
        float x1 = bf2f(qkv[rb + d]);
        float x2 = bf2f(qkv[rb + d + 16]);
        v = x1*cosb[sl*16 + d] - x2*sinb[sl*16 + d];
      } else if (d < 32){
        int i = d - 16;
        float x1 = bf2f(qkv[rb + d - 16]);
        float x2 = bf2f(qkv[rb + d]);
        v = x2*cosb[sl*16 + i] + x1*sinb[sl*16 + i];
      } else if (d < HEAD){
        v = bf2f(qkv[rb + d]);
      } else v = 0.0f;
      outp[obase + (size_t)sl*DSTRIDE + d] = f2bf(v);
    }
  }

  // phase 2: V transpose
  for (int idx = tid; idx < 128*HEAD; idx += 256){
    int sl = idx / HEAD, d = idx - sl*HEAD;
    vtile[sl*88 + d] = qkv[qkrow + (size_t)sl*QKV_N + 2*HIDDEN + h*HEAD + d];
  }
  __syncthreads();
  const size_t vtb = ((size_t)(b*NHEADS + h)*HEAD)*SEQ + s0;
  for (int idx = tid; idx < HEAD*128; idx += 256){
    int d = idx >> 7, sl = idx & 127;
    Vt[vtb + (size_t)d*SEQ + sl] = vtile[sl*88 + d];
  }
}

// ---------------- flash attention (causal) ----------------
// block = (qt,h,b): 4 waves x 32 q-rows = 128 q rows; KT=64.
__global__ __launch_bounds__(256)
void attn_kernel(const unsigned short* __restrict__ Qp,
                 const unsigned short* __restrict__ Kp,
                 const unsigned short* __restrict__ Vt,
                 unsigned short* __restrict__ ctx)
{
  __shared__ __align__(16) unsigned short p_lds[4][32*72];
  const int tid = threadIdx.x;
  const int lane = tid & 63, w = tid >> 6;
  const int l15 = lane & 15, lg = lane >> 4;
  const int qt = blockIdx.x, h = blockIdx.y, b = blockIdx.z;
  const int bh = b*NHEADS + h;
  const int q0 = qt*128 + w*32;

  const unsigned short* Qbase = Qp + ((size_t)bh*SEQ)*DSTRIDE;
  const unsigned short* Kbase = Kp + ((size_t)bh*SEQ)*DSTRIDE;
  const unsigned short* Vbase = Vt + ((size_t)bh*HEAD)*SEQ;

  // Q fragments in registers: rows q0..q0+31, D cols 0..95 (96..127 unused zeros)
  short8 qf[2][3];
  #pragma unroll
  for (int mi=0; mi<2; mi++)
    #pragma unroll
    for (int kc=0; kc<3; kc++)
      qf[mi][kc] = *(const short8*)&Qbase[(size_t)(q0 + mi*16 + l15)*DSTRIDE + kc*32 + lg*8];

  float mrun[2][4], lrun[2][4];
  floatx4 oacc[2][5];
  #pragma unroll
  for (int mi=0;mi<2;mi++){
    #pragma unroll
    for (int r=0;r<4;r++){ mrun[mi][r] = -1e30f; lrun[mi][r] = 0.0f; }
    #pragma unroll
    for (int di=0;di<5;di++) oacc[mi][di] = (floatx4)0.0f;
  }

  const float SC = 0.1118033988749895f * 1.4426950408889634f; // 1/sqrt(80) * log2(e)
  const int nkt = ((q0 + 31) >> 6) + 1;   // causal: tiles with kt*64 <= last q row

  for (int kt = 0; kt < nkt; kt++){
    floatx4 sacc[2][4];
    #pragma unroll
    for (int mi=0;mi<2;mi++)
      #pragma unroll
      for (int ni=0;ni<4;ni++) sacc[mi][ni] = (floatx4)0.0f;

    // S = Q K^T
    #pragma unroll
    for (int kc=0; kc<3; kc++){
      short8 kf[4];
      #pragma unroll
      for (int ni=0; ni<4; ni++)
        kf[ni] = *(const short8*)&Kbase[(size_t)(kt*64 + ni*16 + l15)*DSTRIDE + kc*32 + lg*8];
      #pragma unroll
      for (int mi=0; mi<2; mi++)
        #pragma unroll
        for (int ni=0; ni<4; ni++)
          sacc[mi][ni] = __builtin_amdgcn_mfma_f32_16x16x32_bf16(qf[mi][kc], kf[ni], sacc[mi][ni], 0, 0, 0);
    }

    // online softmax (log2 domain)
    #pragma unroll
    for (int mi=0; mi<2; mi++){
      #pragma unroll
      for (int r=0; r<4; r++){
        int qg = q0 + mi*16 + lg*4 + r;
        float sv[4];
        float pm = -1e30f;
        #pragma unroll
        for (int ni=0; ni<4; ni++){
          int kg = kt*64 + ni*16 + l15;
          float s = sacc[mi][ni][r] * SC;
          if (kg > qg) s = -1e30f;
          sv[ni] = s;
          pm = fmaxf(pm, s);
        }
        pm = fmaxf(pm, __shfl_xor(pm, 1));
        pm = fmaxf(pm, __shfl_xor(pm, 2));
        pm = fmaxf(pm, __shfl_xor(pm, 4));
        pm = fmaxf(pm, __shfl_xor(pm, 8));
        float mold = mrun[mi][r];
        float mnew = fmaxf(mold, pm);
        float alpha = exp2f(mold - mnew);
        float rs = 0.0f;
        #pragma unroll
        for (int ni=0; ni<4; ni++){
          float p = exp2f(sv[ni] - mnew);
          sacc[mi][ni][r] = p;
          rs += p;
        }
        rs += __shfl_xor(rs, 1);
        rs += __shfl_xor(rs, 2);
        rs += __shfl_xor(rs, 4);
        rs += __shfl_xor(rs, 8);
        lrun[mi][r] = lrun[mi][r]*alpha + rs;
        mrun[mi][r] = mnew;
        #pragma unroll
        for (int di=0; di<5; di++) oacc[mi][di][r] *= alpha;
      }
    }

    // P -> LDS (per-wave region, padded stride 72 => conflict-light b128 reads)
    #pragma unroll
    for (int mi=0; mi<2; mi++)
      #pragma unroll
      for (int ni=0; ni<4; ni++)
        #pragma unroll
        for (int r=0; r<4; r++){
          int row = mi*16 + lg*4 + r;
          p_lds[w][row*72 + ni*16 + l15] = f2bf(sacc[mi][ni][r]);
        }

    // O += P V  (V^T fragments straight from global)
    #pragma unroll
    for (int kk=0; kk<2; kk++){
      short8 pa[2];
      #pragma unroll
      for (int mi=0;mi<2;mi++)
        pa[mi] = *(const short8*)&p_lds[w][(mi*16 + l15)*72 + kk*32 + lg*8];
      #pragma unroll
      for (int di=0; di<5; di++){
        short8 vf = *(const short8*)&Vbase[(size_t)(di*16 + l15)*SEQ + kt*64 + kk*32 + lg*8];
        #pragma unroll
        for (int mi=0;mi<2;mi++)
          oacc[mi][di] = __builtin_amdgcn_mfma_f32_16x16x32_bf16(pa[mi], vf, oacc[mi][di], 0, 0, 0);
      }
    }
  }

  // write ctx [B,S,H*80] bf16
  #pragma unroll
  for (int mi=0;mi<2;mi++)
    #pragma unroll
    for (int di=0;di<5;di++)
      #pragma unroll
      for (int r=0;r<4;r++){
        int q = q0 + mi*16 + lg*4 + r;
        float v = oacc[mi][di][r] / lrun[mi][r];
        ctx[((size_t)(b*SEQ + q))*HIDDEN + h*HEAD + di*16 + l15] = f2bf(v);
      }
}

// ---------------- launch ----------------
extern "C" void kernel_launch(void* const* d_in, const int* in_sizes, int n_in,
                              void* d_out, int out_size, void* d_ws, size_t ws_size,
                              hipStream_t stream)
{
  const int*   pos  = (const int*)  d_in[0];
  const float* hid  = (const float*)d_in[1];
  const float* wqkv = (const float*)d_in[2];
  const float* bqkv = (const float*)d_in[3];
  const float* outw = (const float*)d_in[4];
  const float* outb = (const float*)d_in[5];

  char* ws = (char*)d_ws;
  size_t off = 0;
  auto alloc = [&](size_t bytes)->void*{
    void* p = ws + off; off += (bytes + 255) & ~(size_t)255; return p;
  };
  unsigned short* hid_bf  = (unsigned short*)alloc((size_t)M_TOTAL*HIDDEN*2);   // reused as ctx
  unsigned short* wqkv_bf = (unsigned short*)alloc((size_t)QKV_N*HIDDEN*2);
  unsigned short* outw_bf = (unsigned short*)alloc((size_t)HIDDEN*HIDDEN*2);
  unsigned short* qkv_bf  = (unsigned short*)alloc((size_t)M_TOTAL*QKV_N*2);
  unsigned short* Qp      = (unsigned short*)alloc((size_t)BATCH*NHEADS*SEQ*DSTRIDE*2);
  unsigned short* Kp      = (unsigned short*)alloc((size_t)BATCH*NHEADS*SEQ*DSTRIDE*2);
  unsigned short* Vt      = (unsigned short*)alloc((size_t)BATCH*NHEADS*HEAD*SEQ*2);
  if (off > ws_size) return;  // workspace too small; fail loudly via wrong output

  convert_f32_bf16<<<dim3(1024), dim3(256), 0, stream>>>(hid,  hid_bf,  M_TOTAL*HIDDEN/4);
  convert_f32_bf16<<<dim3(2048), dim3(256), 0, stream>>>(wqkv, wqkv_bf, QKV_N*HIDDEN/4);
  convert_f32_bf16<<<dim3(1024), dim3(256), 0, stream>>>(outw, outw_bf, HIDDEN*HIDDEN/4);

  gemm_bt<true><<<dim3(QKV_N/128, M_TOTAL/128), dim3(256), 0, stream>>>(
      hid_bf, wqkv_bf, bqkv, (void*)qkv_bf, M_TOTAL, QKV_N, HIDDEN);

  rope_scatter<<<dim3(BATCH*NHEADS*16), dim3(256), 0, stream>>>(qkv_bf, pos, Qp, Kp, Vt);

  unsigned short* ctx = hid_bf;  // hidden_bf dead after QKV GEMM
  attn_kernel<<<dim3(SEQ/128, NHEADS, BATCH), dim3(256), 0, stream>>>(Qp, Kp, Vt, ctx);

  gemm_bt<false><<<dim3(HIDDEN/128, M_TOTAL/128), dim3(256), 0, stream>>>(
      ctx, outw_bf, outb, d_out, M_TOTAL, HIDDEN, HIDDEN);
}